// Round 1
// baseline (321.025 us; speedup 1.0000x reference)
//
#include <hip/hip_runtime.h>
#include <stdint.h>

#define NB 16
#define NC 256
#define NH 48
#define NW 64
#define ND 21
#define HW (NH * NW)

typedef __bf16 bf16x8 __attribute__((ext_vector_type(8)));
typedef float f32x4 __attribute__((ext_vector_type(4)));

// LDS layout: [x][c] bf16, c-chunks of 8 elements (16B), low-3 chunk bits
// XOR-swizzled by (x&7) so frag reads (ds_read_b128) and staging writes both
// spread across banks. Row stride 256 elems (512B) -> no pad, 32KB/buffer.
__device__ __forceinline__ int sw_addr(int x, int chunk) {
    int cs = (chunk & ~7) | ((chunk ^ x) & 7);
    return x * 256 + (cs << 3);
}

__device__ __forceinline__ unsigned short to_bf16(float f) {
    uint32_t u = __float_as_uint(f);
    uint32_t r = (u + 0x7FFFu + ((u >> 16) & 1u)) >> 16;  // RNE
    return (unsigned short)r;
}

__global__ void __launch_bounds__(256, 2)
corr_kernel(const float* __restrict__ in1, const float* __restrict__ in2,
            float* __restrict__ out) {
    __shared__ unsigned short s1[NW * NC];  // in1[b,:,y,:]  as [x][c] bf16
    __shared__ unsigned short s2[NW * NC];  // in2[b,:,ys,:] as [x'][c] bf16

    const int tid  = threadIdx.x;
    const int b    = blockIdx.x / NH;
    const int y    = blockIdx.x % NH;
    const int lane = tid & 63;
    const int wave = tid >> 6;   // 0..3
    const int m_lo = lane & 15;
    const int quad = lane >> 4;
    const int asub = wave >> 1;  // M-supertile (x  in [32*asub, 32*asub+32))
    const int bsub = wave & 1;   // N-supertile (x' in [32*bsub, 32*bsub+32))

    // ---- stage s1 (once per block): coalesced fp32 reads, bf16 into [x][c]
    {
        const int x  = tid & 63;
        const int c0 = tid >> 6;
        const float* p = in1 + ((size_t)b * NC * NH + y) * NW + x;
#pragma unroll 8
        for (int c = c0; c < NC; c += 4) {
            float f = p[(size_t)c * HW];
            s1[sw_addr(x, c >> 3) + (c & 7)] = to_bf16(f);
        }
    }
    __syncthreads();

    // ---- cache all A fragments for this wave's two M-tiles (64 VGPR/lane)
    // A-layout (verified m120/m89): A[m = lane&15][k = quad*8 + j]
    bf16x8 afrag[2][8];
#pragma unroll
    for (int mm = 0; mm < 2; ++mm) {
        const int x = 32 * asub + 16 * mm + m_lo;
#pragma unroll
        for (int kb = 0; kb < 8; ++kb)
            afrag[mm][kb] = *(const bf16x8*)&s1[sw_addr(x, 4 * kb + quad)];
    }

    const float scale = 1.0f / 256.0f;

    for (int dyi = 0; dyi < ND; ++dyi) {
        const int ys = y + 2 * dyi - 20;
        float* ob = out + (((size_t)b * (ND * ND) + (size_t)dyi * ND) * NH + y) * NW;

        if ((unsigned)ys >= (unsigned)NH) {  // whole dy-plane is zero
            for (int i = tid; i < ND * NW; i += 256)
                ob[(size_t)(i >> 6) * HW + (i & 63)] = 0.0f;
            continue;
        }

        __syncthreads();  // prev iteration's B-frag reads done before restage
        {
            const int x  = tid & 63;
            const int c0 = tid >> 6;
            const float* p = in2 + ((size_t)b * NC * NH + ys) * NW + x;
#pragma unroll 8
            for (int c = c0; c < NC; c += 4) {
                float f = p[(size_t)c * HW];
                s2[sw_addr(x, c >> 3) + (c & 7)] = to_bf16(f);
            }
        }
        __syncthreads();

        // ---- 2x2 MFMA tiles (32x32 supertile), K=256 in 8 steps
        f32x4 acc[2][2];
#pragma unroll
        for (int mm = 0; mm < 2; ++mm)
#pragma unroll
            for (int nn = 0; nn < 2; ++nn)
                acc[mm][nn] = (f32x4){0.f, 0.f, 0.f, 0.f};

#pragma unroll
        for (int nn = 0; nn < 2; ++nn) {
            const int xp = 32 * bsub + 16 * nn + m_lo;  // B[k][n=lane&15]
#pragma unroll
            for (int kb = 0; kb < 8; ++kb) {
                bf16x8 bfrag = *(const bf16x8*)&s2[sw_addr(xp, 4 * kb + quad)];
                acc[0][nn] = __builtin_amdgcn_mfma_f32_16x16x32_bf16(
                    afrag[0][kb], bfrag, acc[0][nn], 0, 0, 0);
                acc[1][nn] = __builtin_amdgcn_mfma_f32_16x16x32_bf16(
                    afrag[1][kb], bfrag, acc[1][nn], 0, 0, 0);
            }
        }

        // ---- band extraction: D[row=x within tile][col=x'], keep even
        // x'-x in [-20,20]. C/D layout (verified m89/m91):
        // col = lane&15, row = quad*4 + reg
#pragma unroll
        for (int mm = 0; mm < 2; ++mm) {
#pragma unroll
            for (int nn = 0; nn < 2; ++nn) {
                const int xb = 32 * asub + 16 * mm + 4 * quad;
                const int xp = 32 * bsub + 16 * nn + m_lo;
#pragma unroll
                for (int r = 0; r < 4; ++r) {
                    const int x = xb + r;
                    const int d = xp - x;
                    if (d >= -20 && d <= 20 && !(d & 1))
                        ob[(size_t)((d + 20) >> 1) * HW + x] = acc[mm][nn][r] * scale;
                }
            }
        }

        // ---- zero-fill x positions where x+dx is out of [0,64)
        for (int i = tid; i < ND * 20; i += 256) {
            const int dxi = i / 20;
            const int j   = i - dxi * 20;
            const int dx  = 2 * dxi - 20;
            const int a   = dx < 0 ? -dx : dx;
            if (j < a) {
                const int x = dx < 0 ? j : (NW - dx + j);
                ob[(size_t)dxi * HW + x] = 0.0f;
            }
        }
    }
}

extern "C" void kernel_launch(void* const* d_in, const int* in_sizes, int n_in,
                              void* d_out, int out_size, void* d_ws, size_t ws_size,
                              hipStream_t stream) {
    const float* in1 = (const float*)d_in[0];
    const float* in2 = (const float*)d_in[1];
    float* out = (float*)d_out;
    corr_kernel<<<dim3(NB * NH), dim3(256), 0, stream>>>(in1, in2, out);
}

// Round 2
// 243.782 us; speedup vs baseline: 1.3169x; 1.3169x over previous
//
#include <hip/hip_runtime.h>
#include <stdint.h>

#define NB 16
#define NC 256
#define NH 48
#define NW 64
#define ND 21
#define HW (NH * NW)
#define ROW_ELEMS (NW * NC)  // one (b,y) row as [x][c] bf16: 16384 elems = 32KB

typedef __bf16 bf16x8 __attribute__((ext_vector_type(8)));
typedef float f32x4 __attribute__((ext_vector_type(4)));

// LDS/row layout: [x][c] bf16, c in 16B chunks of 8, low-3 chunk bits XORed
// with (x&7) so ds_read_b128 frag reads spread banks. 512B per x-row.
__device__ __forceinline__ int sw_addr(int x, int chunk) {
    int cs = (chunk & ~7) | ((chunk ^ x) & 7);
    return x * 256 + (cs << 3);
}

__device__ __forceinline__ unsigned short to_bf16(float f) {
    uint32_t u = __float_as_uint(f);
    return (unsigned short)((u + 0x7FFFu + ((u >> 16) & 1u)) >> 16);  // RNE
}

// async 32KB row copy: global (pre-swizzled) -> LDS, 8 x 16B per thread
__device__ __forceinline__ void stage_async(const unsigned short* __restrict__ g,
                                            unsigned short* l, int tid) {
#pragma unroll
    for (int i = 0; i < 8; ++i) {
        const int e = (i * 256 + tid) * 8;
        __builtin_amdgcn_global_load_lds(
            (const __attribute__((address_space(1))) void*)(g + e),
            (__attribute__((address_space(3))) void*)(l + e), 16, 0, 0);
    }
}

// ---------- pre-pass: in2 fp32 [b][c][h][w] -> ws bf16 rows (swizzle baked) --
__global__ void __launch_bounds__(256, 2)
convert_in2(const float* __restrict__ in2, unsigned short* __restrict__ ws) {
    __shared__ unsigned short s[ROW_ELEMS];
    const int tid = threadIdx.x;
    const int b = blockIdx.x / NH, y = blockIdx.x % NH;
    const int x = tid & 63, c0 = tid >> 6;
    const float* p = in2 + ((size_t)b * NC * NH + y) * NW + x;
#pragma unroll 8
    for (int c = c0; c < NC; c += 4)
        s[sw_addr(x, c >> 3) + (c & 7)] = to_bf16(p[(size_t)c * HW]);
    __syncthreads();
    unsigned short* wr = ws + ((size_t)b * NH + y) * ROW_ELEMS;
#pragma unroll
    for (int i = 0; i < 8; ++i) {
        const int e = (i * 256 + tid) * 8;
        *(bf16x8*)(wr + e) = *(const bf16x8*)(s + e);  // linear, coalesced
    }
}

// ---------- main: one block per (b,y); wave = M64 x N16; dbuf in2 rows ------
__global__ void __launch_bounds__(256, 2)
corr_main(const float* __restrict__ in1, const unsigned short* __restrict__ ws,
          float* __restrict__ out) {
    __shared__ unsigned short sb[2][ROW_ELEMS];  // 64KB -> 2 blocks/CU
    const int tid  = threadIdx.x;
    const int b    = blockIdx.x / NH, y = blockIdx.x % NH;
    const int lane = tid & 63, wave = tid >> 6;
    const int m_lo = lane & 15, quad = lane >> 4;

    // ---- stage in1 row -> sb[0] (fp32 convert path, once per block)
    {
        const int x = tid & 63, c0 = tid >> 6;
        const float* p = in1 + ((size_t)b * NC * NH + y) * NW + x;
#pragma unroll 8
        for (int c = c0; c < NC; c += 4)
            sb[0][sw_addr(x, c >> 3) + (c & 7)] = to_bf16(p[(size_t)c * HW]);
    }
    __syncthreads();

    // ---- cache A for ALL 4 M-tiles: A[m=lane&15][k=quad*8+j], k-chunk kb
    bf16x8 afrag[4][8];
#pragma unroll
    for (int mm = 0; mm < 4; ++mm) {
        const int x = 16 * mm + m_lo;
#pragma unroll
        for (int kb = 0; kb < 8; ++kb)
            afrag[mm][kb] = *(const bf16x8*)&sb[0][sw_addr(x, 4 * kb + quad)];
    }

    // ---- valid dy range is contiguous; zero the invalid planes up front
    const int d0 = (y >= 20) ? 0 : (21 - y) >> 1;
    const int d1 = min(20, (67 - y) >> 1);
    float* outbase = out + (((size_t)b * (ND * ND)) * NH + (size_t)y) * NW;
    for (int dyi = 0; dyi < ND; ++dyi) {
        if (dyi >= d0 && dyi <= d1) continue;
        float* ob = outbase + (size_t)dyi * ND * HW;
        for (int i = tid; i < ND * NW; i += 256)
            ob[(size_t)(i >> 6) * HW + (i & 63)] = 0.0f;
    }
    __syncthreads();  // everyone done reading sb[0] before it's recycled

    const unsigned short* wsb = ws + (size_t)b * NH * ROW_ELEMS;
    stage_async(wsb + (size_t)(y - 20 + 2 * d0) * ROW_ELEMS, &sb[0][0], tid);

    const float scale = 1.0f / 256.0f;
    const int xp = 16 * wave + m_lo;  // this lane's B column (x')
    int cur = 0;

    for (int dyi = d0; dyi <= d1; ++dyi) {
        __syncthreads();  // drains vmcnt -> sb[cur] is loaded & visible
        if (dyi < d1)     // prefetch next row; overlaps with compute below
            stage_async(wsb + (size_t)(y - 20 + 2 * (dyi + 1)) * ROW_ELEMS,
                        &sb[cur ^ 1][0], tid);

        const unsigned short* s2 = &sb[cur][0];
        f32x4 acc[4];
#pragma unroll
        for (int mm = 0; mm < 4; ++mm) acc[mm] = (f32x4){0.f, 0.f, 0.f, 0.f};

#pragma unroll
        for (int kb = 0; kb < 8; ++kb) {
            bf16x8 bf = *(const bf16x8*)&s2[sw_addr(xp, 4 * kb + quad)];
            acc[0] = __builtin_amdgcn_mfma_f32_16x16x32_bf16(afrag[0][kb], bf, acc[0], 0, 0, 0);
            acc[1] = __builtin_amdgcn_mfma_f32_16x16x32_bf16(afrag[1][kb], bf, acc[1], 0, 0, 0);
            acc[2] = __builtin_amdgcn_mfma_f32_16x16x32_bf16(afrag[2][kb], bf, acc[2], 0, 0, 0);
            acc[3] = __builtin_amdgcn_mfma_f32_16x16x32_bf16(afrag[3][kb], bf, acc[3], 0, 0, 0);
        }

        // ---- band extraction: row = 16*mm + quad*4 + r (=x), col = xp
        float* ob = outbase + (size_t)dyi * ND * HW;
#pragma unroll
        for (int mm = 0; mm < 4; ++mm) {
            const int xb = 16 * mm + 4 * quad;
#pragma unroll
            for (int r = 0; r < 4; ++r) {
                const int x = xb + r;
                const int d = xp - x;
                if (d >= -20 && d <= 20 && !(d & 1))
                    ob[(size_t)((d + 20) >> 1) * HW + x] = acc[mm][r] * scale;
            }
        }
        // ---- zero-fill x where x+dx out of [0,64)
        for (int i = tid; i < ND * 20; i += 256) {
            const int dxi = i / 20, j = i - dxi * 20;
            const int dx = 2 * dxi - 20, a = dx < 0 ? -dx : dx;
            if (j < a) {
                const int x = dx < 0 ? j : (NW - dx + j);
                ob[(size_t)dxi * HW + x] = 0.0f;
            }
        }
        cur ^= 1;
    }
}

// ---------- fallback (round-1 kernel) if ws is too small ---------------------
__global__ void __launch_bounds__(256, 2)
corr_fallback(const float* __restrict__ in1, const float* __restrict__ in2,
              float* __restrict__ out) {
    __shared__ unsigned short s1[ROW_ELEMS];
    __shared__ unsigned short s2[ROW_ELEMS];
    const int tid = threadIdx.x;
    const int b = blockIdx.x / NH, y = blockIdx.x % NH;
    const int lane = tid & 63, wave = tid >> 6;
    const int m_lo = lane & 15, quad = lane >> 4;
    const int asub = wave >> 1, bsub = wave & 1;
    {
        const int x = tid & 63, c0 = tid >> 6;
        const float* p = in1 + ((size_t)b * NC * NH + y) * NW + x;
        for (int c = c0; c < NC; c += 4)
            s1[sw_addr(x, c >> 3) + (c & 7)] = to_bf16(p[(size_t)c * HW]);
    }
    __syncthreads();
    bf16x8 afrag[2][8];
    for (int mm = 0; mm < 2; ++mm) {
        const int x = 32 * asub + 16 * mm + m_lo;
        for (int kb = 0; kb < 8; ++kb)
            afrag[mm][kb] = *(const bf16x8*)&s1[sw_addr(x, 4 * kb + quad)];
    }
    const float scale = 1.0f / 256.0f;
    for (int dyi = 0; dyi < ND; ++dyi) {
        const int ys = y + 2 * dyi - 20;
        float* ob = out + (((size_t)b * (ND * ND) + (size_t)dyi * ND) * NH + y) * NW;
        if ((unsigned)ys >= (unsigned)NH) {
            for (int i = tid; i < ND * NW; i += 256)
                ob[(size_t)(i >> 6) * HW + (i & 63)] = 0.0f;
            continue;
        }
        __syncthreads();
        {
            const int x = tid & 63, c0 = tid >> 6;
            const float* p = in2 + ((size_t)b * NC * NH + ys) * NW + x;
            for (int c = c0; c < NC; c += 4)
                s2[sw_addr(x, c >> 3) + (c & 7)] = to_bf16(p[(size_t)c * HW]);
        }
        __syncthreads();
        f32x4 acc[2][2];
        for (int mm = 0; mm < 2; ++mm)
            for (int nn = 0; nn < 2; ++nn) acc[mm][nn] = (f32x4){0.f, 0.f, 0.f, 0.f};
        for (int nn = 0; nn < 2; ++nn) {
            const int xp = 32 * bsub + 16 * nn + m_lo;
            for (int kb = 0; kb < 8; ++kb) {
                bf16x8 bfrag = *(const bf16x8*)&s2[sw_addr(xp, 4 * kb + quad)];
                acc[0][nn] = __builtin_amdgcn_mfma_f32_16x16x32_bf16(afrag[0][kb], bfrag, acc[0][nn], 0, 0, 0);
                acc[1][nn] = __builtin_amdgcn_mfma_f32_16x16x32_bf16(afrag[1][kb], bfrag, acc[1][nn], 0, 0, 0);
            }
        }
        for (int mm = 0; mm < 2; ++mm)
            for (int nn = 0; nn < 2; ++nn) {
                const int xb = 32 * asub + 16 * mm + 4 * quad;
                const int xp = 32 * bsub + 16 * nn + m_lo;
                for (int r = 0; r < 4; ++r) {
                    const int x = xb + r, d = xp - x;
                    if (d >= -20 && d <= 20 && !(d & 1))
                        ob[(size_t)((d + 20) >> 1) * HW + x] = acc[mm][nn][r] * scale;
                }
            }
        for (int i = tid; i < ND * 20; i += 256) {
            const int dxi = i / 20, j = i - dxi * 20;
            const int dx = 2 * dxi - 20, a = dx < 0 ? -dx : dx;
            if (j < a) {
                const int x = dx < 0 ? j : (NW - dx + j);
                ob[(size_t)dxi * HW + x] = 0.0f;
            }
        }
    }
}

extern "C" void kernel_launch(void* const* d_in, const int* in_sizes, int n_in,
                              void* d_out, int out_size, void* d_ws, size_t ws_size,
                              hipStream_t stream) {
    const float* in1 = (const float*)d_in[0];
    const float* in2 = (const float*)d_in[1];
    float* out = (float*)d_out;
    const size_t need = (size_t)NB * NH * ROW_ELEMS * sizeof(unsigned short);
    if (ws_size >= need) {
        convert_in2<<<dim3(NB * NH), dim3(256), 0, stream>>>(in2, (unsigned short*)d_ws);
        corr_main<<<dim3(NB * NH), dim3(256), 0, stream>>>(in1, (const unsigned short*)d_ws, out);
    } else {
        corr_fallback<<<dim3(NB * NH), dim3(256), 0, stream>>>(in1, in2, out);
    }
}